// Round 14
// baseline (440.340 us; speedup 1.0000x reference)
//
#include <hip/hip_runtime.h>
#include <hip/hip_bf16.h>

// GCN 3-layer: gcn_norm -> (GCNConv, ELU) x2 -> GCNConv
// N=100000, E=3200000, dims 128->32->64->128.
// agg is linear => aggregate in the SMALLER feature dim per layer:
//   L1: t1 = x@W1 (128->32); a1 = ELU(agg(t1) + b1)          [gather F=32]
//   L2: s2 = agg(a1);        h2 = ELU(s2@W2 + b2)            [gather F=32]
//   L3: s3 = agg(h2);        out = s3@W3 + b3                [gather F=64]
//
// CSR build: bucketed 2-level counting sort (k_hist -> k_bscan ->
// k_scatter -> k_nodecnt -> k_fill).
// epk[e] = src(17b) | q15(dinv[src]*ew)<<17  (4B/edge, precomputed w').
//
// LESSONS:
//  - r2: LDS f32 atomicAdd agg = 12x slower. Never E*F-scale ds_add.
//  - r3: agg near compulsory-traffic ceiling; bytes are the lever.
//  - r4: bf16 intermediate buffers (storage only, fp32 accum) -> -93us.
//  - r5/r6: scatter fixed via batch-load-then-process + 782 blocks.
//  - r8: dinv[src] inside agg loop = wash; keep hot loops minimal.
//  - r9: 4B epk w/ precomputed q15(dinv*ew): aggs off the top.
//  - r10/r11: GEMM bank-conflict map swap + KC=32 staging: 452.9->425.4.
//  - r12 (REVERTED): XCD feature-chunking cut HBM 158->64MB but made
//    gathers 16B-per-2-lanes (32 partial lines/instr) -> vmem request-
//    rate-bound, 52.7->133.6us. Keep >=cache-line-contiguous gathers.
//  - r14 (this): agg VALU is dominated by per-gather overhead (addr
//    calc/issue), not FLOPs (math-only VALU ~10us vs 27us busy).
//    Widen lane gathers uint2->uint4 (16B = 8 bf16/lane): gather+addr
//    instruction count halves, w-decode halves; per-edge line count
//    unchanged (128B/64B contiguous). Cost: degree divergence over 2x
//    nodes/wave (~-7% wave efficiency), VGPR ~70.
// Inputs: fp32 (probed vs bf16), edge_index i64 (probed vs i32). Output fp32.

constexpr int N = 100000;
constexpr int E = 3200000;

constexpr int BSHIFT = 7;
constexpr int BSIZE = 128;                       // nodes per bucket
constexpr int NBKT = (N + BSIZE - 1) / BSIZE;    // 782

constexpr float FIX_SCALE = 16777216.0f;         // 2^24
constexpr float Q15 = 32768.0f;

constexpr int HIST_EPB = 4096;                   // edges per block, hist
constexpr int SC_EPB = 4096;                     // edges per block, scatter

__device__ __forceinline__ float ldf(const void* p, int isbf, size_t i) {
    return isbf ? __bfloat162float(((const __hip_bfloat16*)p)[i])
                : ((const float*)p)[i];
}

__device__ __forceinline__ int ld_idx(const void* ei, int is64, size_t pos) {
    return is64 ? (int)((const long long*)ei)[pos] : ((const int*)ei)[pos];
}

// --- bf16x4 pack/unpack (manual RNE, no API dependence) ---
__device__ __forceinline__ float4 bf4tof4(uint2 u) {
    float4 r;
    r.x = __uint_as_float(u.x << 16);
    r.y = __uint_as_float(u.x & 0xffff0000u);
    r.z = __uint_as_float(u.y << 16);
    r.w = __uint_as_float(u.y & 0xffff0000u);
    return r;
}
__device__ __forceinline__ unsigned short f2bf(float f) {
    unsigned u = __float_as_uint(f);
    unsigned rnd = 0x7fffu + ((u >> 16) & 1u);
    return (unsigned short)((u + rnd) >> 16);
}
__device__ __forceinline__ unsigned packbf2(float a, float b) {
    return (unsigned)f2bf(a) | ((unsigned)f2bf(b) << 16);
}
__device__ __forceinline__ uint2 f4tobf4(float4 v) {
    uint2 r;
    r.x = packbf2(v.x, v.y);
    r.y = packbf2(v.z, v.w);
    return r;
}

// flags[0] = is64 (edge_index), flags[1] = isbf (float tensors)
// also zeroes the bucket-count array (runs before k_hist on the stream)
__global__ void k_probe(const void* ei, const void* x, int* flags, int* bkt_cnt) {
    __shared__ int bad64, bigcnt;
    int t = threadIdx.x;
    if (t == 0) { bad64 = 0; bigcnt = 0; }
    __syncthreads();
    long long v = ((const long long*)ei)[t];
    if (v < 0 || v >= (long long)N) atomicAdd(&bad64, 1);
    const unsigned short* u = (const unsigned short*)x;
    int big = 0;
    for (int i = t * 16; i < t * 16 + 16; i++) {
        int e = (u[i] >> 7) & 0xFF;
        if (e >= 133) big++;
    }
    atomicAdd(&bigcnt, big);
    for (int i = t; i < NBKT; i += 256) bkt_cnt[i] = 0;
    __syncthreads();
    if (t == 0) { flags[0] = (bad64 == 0) ? 1 : 0; flags[1] = (bigcnt < 40) ? 1 : 0; }
}

// bucket histogram: batch-load targets into registers, then LDS atomics,
// one global atomic per (block,bucket)
__global__ __launch_bounds__(512) void k_hist(const void* ei, const int* flags,
                                              int* bkt_cnt) {
    constexpr int EPT = HIST_EPB / 512;          // 8
    __shared__ int h[NBKT];
    int t = threadIdx.x;
    for (int i = t; i < NBKT; i += 512) h[i] = 0;
    __syncthreads();
    int is64 = flags[0];
    size_t eb = (size_t)blockIdx.x * HIST_EPB;
    int nb = (int)min((size_t)HIST_EPB, (size_t)E - eb);
    int cc[EPT];
#pragma unroll
    for (int k = 0; k < EPT; k++) {
        int idx = t + k * 512;
        cc[k] = (idx < nb) ? ld_idx(ei, is64, (size_t)E + eb + idx) : -1;
    }
#pragma unroll
    for (int k = 0; k < EPT; k++)
        if (cc[k] >= 0) atomicAdd(&h[cc[k] >> BSHIFT], 1);
    __syncthreads();
    for (int i = t; i < NBKT; i += 512) {
        int v = h[i];
        if (v) atomicAdd(&bkt_cnt[i], v);
    }
}

// single-block exclusive scan over NBKT buckets -> bkt_off, bkt_cur
__global__ void k_bscan(const int* bkt_cnt, int* bkt_off, int* bkt_cur) {
    __shared__ int s[256];
    int t = threadIdx.x;
    int v[4]; int sum = 0;
#pragma unroll
    for (int j = 0; j < 4; j++) {
        int i = t * 4 + j;
        v[j] = (i < NBKT) ? bkt_cnt[i] : 0;
        sum += v[j];
    }
    s[t] = sum; __syncthreads();
    for (int st = 1; st < 256; st <<= 1) {
        int add = (t >= st) ? s[t - st] : 0;
        __syncthreads();
        s[t] += add;
        __syncthreads();
    }
    int excl = s[t] - sum;
#pragma unroll
    for (int j = 0; j < 4; j++) {
        int i = t * 4 + j;
        if (i < NBKT) { bkt_off[i] = excl; bkt_cur[i] = excl; excl += v[j]; }
    }
    if (t == 0) bkt_off[NBKT] = E;
}

// bucket-sort edges into tmp[]: batch-load (r,c,w) into registers ONCE,
// then per-block LDS histogram + run reservation + placement, all from
// registers. tmp entry: .x = r | (c&127)<<17  (r<2^17), .y = w bits
__global__ __launch_bounds__(512) void k_scatter(const void* ei, const int* flags,
                                                 const void* ew, int* bkt_cur,
                                                 int2* tmp) {
    constexpr int EPT = SC_EPB / 512;            // 8
    __shared__ int h[NBKT];
    __shared__ int base_s[NBKT];
    int t = threadIdx.x;
    for (int i = t; i < NBKT; i += 512) h[i] = 0;
    __syncthreads();
    int is64 = flags[0], isbf = flags[1];
    size_t eb = (size_t)blockIdx.x * SC_EPB;
    int nb = (int)min((size_t)SC_EPB, (size_t)E - eb);
    int rr[EPT], cc[EPT]; float ww[EPT];
    // batched, coalesced, independent loads; single drain
#pragma unroll
    for (int k = 0; k < EPT; k++) {
        int idx = t + k * 512;
        if (idx < nb) {
            size_t e = eb + idx;
            rr[k] = ld_idx(ei, is64, e);
            cc[k] = ld_idx(ei, is64, (size_t)E + e);
            ww[k] = ldf(ew, isbf, e);
        } else {
            rr[k] = 0; cc[k] = -1; ww[k] = 0.f;
        }
    }
    // pass 1: local histogram (registers -> LDS atomics, pipelined)
#pragma unroll
    for (int k = 0; k < EPT; k++)
        if (cc[k] >= 0) atomicAdd(&h[cc[k] >> BSHIFT], 1);
    __syncthreads();
    // reserve a dense run per bucket
    for (int i = t; i < NBKT; i += 512) {
        int v = h[i];
        base_s[i] = v ? atomicAdd(&bkt_cur[i], v) : 0;
    }
    __syncthreads();
    for (int i = t; i < NBKT; i += 512) h[i] = 0;
    __syncthreads();
    // pass 2: place edges within reserved runs (registers -> global)
#pragma unroll
    for (int k = 0; k < EPT; k++) {
        if (cc[k] >= 0) {
            int b = cc[k] >> BSHIFT;
            int loc = atomicAdd(&h[b], 1);
            int pos = base_s[b] + loc;
            tmp[pos] = make_int2(rr[k] | ((cc[k] & (BSIZE - 1)) << 17),
                                 __float_as_int(ww[k]));
        }
    }
}

// per bucket: node counts + fixed-point weight sums (LDS int atomics),
// 128-wide LDS scan -> offsets; dinv = rsqrt(1 + wsum) (bit-identical
// to the original packed scheme)
__global__ __launch_bounds__(256) void k_nodecnt(const int2* __restrict__ tmp,
                                                 const int* __restrict__ bkt_off,
                                                 int* __restrict__ counts,
                                                 int* __restrict__ offsets,
                                                 float* __restrict__ dinv) {
    __shared__ int cnt_s[BSIZE];
    __shared__ unsigned int wfx_s[BSIZE];
    __shared__ int sc_s[BSIZE];
    int t = threadIdx.x;
    int b = blockIdx.x;
    if (t < BSIZE) { cnt_s[t] = 0; wfx_s[t] = 0u; }
    __syncthreads();
    int s0 = bkt_off[b], s1 = bkt_off[b + 1];
    for (int p = s0 + t; p < s1; p += 256) {
        int2 ev = tmp[p];
        int c7 = (int)(((unsigned)ev.x) >> 17);
        float w = __int_as_float(ev.y);
        atomicAdd(&cnt_s[c7], 1);
        atomicAdd(&wfx_s[c7], (unsigned)__float2uint_rn(w * FIX_SCALE));
    }
    __syncthreads();
    if (t < BSIZE) sc_s[t] = cnt_s[t];
    __syncthreads();
    for (int st = 1; st < BSIZE; st <<= 1) {
        int add = (t < BSIZE && t >= st) ? sc_s[t - st] : 0;
        __syncthreads();
        if (t < BSIZE) sc_s[t] += add;
        __syncthreads();
    }
    if (t < BSIZE) {
        int node = b * BSIZE + t;
        if (node < N) {
            int c = cnt_s[t];
            offsets[node] = s0 + sc_s[t] - c;   // bucket base + exclusive
            counts[node] = c;
            float deg = 1.0f + (float)wfx_s[t] * (1.0f / FIX_SCALE);
            dinv[node] = rsqrtf(deg);
        }
    }
}

// per bucket: fill 4B CSR epk[pos] = src | q15(dinv[src]*ew)<<17.
// w' = dinv*ew < 1 strictly (dinv<=1, ew<1) so q15 fits 15 bits
// (clamped at 32767 for the rounding edge case). dinv table reads are
// random but 400KB L2-resident. Destination range is the bucket's
// contiguous slice of epk -> block-private, dense.
__global__ __launch_bounds__(256) void k_fill(const int2* __restrict__ tmp,
                                              const int* __restrict__ bkt_off,
                                              const int* __restrict__ offsets,
                                              const float* __restrict__ dinv,
                                              unsigned* __restrict__ epk) {
    __shared__ int lcur[BSIZE];
    int t = threadIdx.x;
    int b = blockIdx.x;
    if (t < BSIZE) {
        int node = b * BSIZE + t;
        lcur[t] = (node < N) ? offsets[node] : 0;
    }
    __syncthreads();
    int s0 = bkt_off[b], s1 = bkt_off[b + 1];
    for (int p = s0 + t; p < s1; p += 256) {
        int2 ev = tmp[p];
        unsigned px = (unsigned)ev.x;
        int r = (int)(px & 0x1FFFFu);
        int c7 = (int)(px >> 17);
        float w = __int_as_float(ev.y);
        float nr = dinv[r] * w;
        unsigned q = __float2uint_rn(nr * Q15);
        if (q > 32767u) q = 32767u;
        int pos = atomicAdd(&lcur[c7], 1);
        epk[pos] = (unsigned)r | (q << 17);
    }
}

// --- register-blocked GEMM: H[N,FOUT] = X[N,FIN] @ W[FIN,FOUT] (+b, ELU)
// XMODE: 1 = external input (runtime fp32/bf16 probe), 2 = internal bf16.
// OBF: write bf16 (internal buffer) vs fp32 (final output).
// KC: k-chunk for LDS staging. Thread map trow=t%TROWS (r10 fix).
template <int FIN, int FOUT, int TM, int TN, int KC, int XMODE, bool OBF,
          bool BIAS, bool ELU>
__global__ __launch_bounds__(256) void k_gemm(const void* __restrict__ X,
                                              const void* __restrict__ W,
                                              const void* __restrict__ bias,
                                              const int* __restrict__ flags,
                                              void* __restrict__ H) {
    constexpr int TCOLS = FOUT / TN;
    constexpr int TROWS = 256 / TCOLS;
    constexpr int BR = TROWS * TM;
    __shared__ float wl[KC * FOUT];
    __shared__ float xt[KC][BR + 1];
    int t = threadIdx.x;
    int isbf = flags[1];
    int base = blockIdx.x * BR;
    int trow = t % TROWS, tcol = t / TROWS;   // bank-conflict-free map
    int r0 = trow * TM, c0 = tcol * TN;
    float acc[TM][TN] = {};

    for (int kc = 0; kc < FIN; kc += KC) {
        if (kc) __syncthreads();              // previous chunk fully read
        // stage W rows [kc, kc+KC)
        if (!isbf) {
            const float4* W4 = (const float4*)W;
            float4* wl4 = (float4*)wl;
            for (int i = t; i < KC * FOUT / 4; i += 256)
                wl4[i] = W4[(size_t)kc * FOUT / 4 + i];
        } else {
            for (int i = t; i < KC * FOUT; i += 256)
                wl[i] = __bfloat162float(((const __hip_bfloat16*)W)[(size_t)kc * FOUT + i]);
        }
        // stage X columns [kc, kc+KC), transposed into xt[k][row]
        if (XMODE == 2) {
            const uint2* X2 = (const uint2*)X;
            for (int i = t; i < BR * KC / 4; i += 256) {
                int row = i / (KC / 4);
                int kq = i % (KC / 4);
                int node = base + row;
                uint2 u = make_uint2(0u, 0u);
                if (node < N) u = X2[(size_t)node * (FIN / 4) + kc / 4 + kq];
                float4 v = bf4tof4(u);
                int k = kq * 4;
                xt[k][row] = v.x; xt[k + 1][row] = v.y;
                xt[k + 2][row] = v.z; xt[k + 3][row] = v.w;
            }
        } else if (!isbf) {
            const float4* X4 = (const float4*)X;
            for (int i = t; i < BR * KC / 4; i += 256) {
                int row = i / (KC / 4);
                int kq = i % (KC / 4);
                int node = base + row;
                float4 v = make_float4(0.f, 0.f, 0.f, 0.f);
                if (node < N) v = X4[(size_t)node * (FIN / 4) + kc / 4 + kq];
                int k = kq * 4;
                xt[k][row] = v.x; xt[k + 1][row] = v.y;
                xt[k + 2][row] = v.z; xt[k + 3][row] = v.w;
            }
        } else {
            for (int i = t; i < BR * KC; i += 256) {
                int row = i / KC, k = i % KC;
                int node = base + row;
                float v = (node < N)
                    ? __bfloat162float(((const __hip_bfloat16*)X)[(size_t)node * FIN + kc + k])
                    : 0.f;
                xt[k][row] = v;
            }
        }
        __syncthreads();

#pragma unroll 4
        for (int k = 0; k < KC; k++) {
            float a[TM], b[TN];
#pragma unroll
            for (int m = 0; m < TM; m++) a[m] = xt[k][r0 + m];
#pragma unroll
            for (int n = 0; n < TN; n++) b[n] = wl[k * FOUT + c0 + n];
#pragma unroll
            for (int m = 0; m < TM; m++)
#pragma unroll
                for (int n = 0; n < TN; n++) acc[m][n] += a[m] * b[n];
        }
    }

#pragma unroll
    for (int m = 0; m < TM; m++) {
        int node = base + r0 + m;
        if (node >= N) continue;
        float vv[TN];
#pragma unroll
        for (int n = 0; n < TN; n++) {
            float v = acc[m][n];
            if (BIAS) v += ldf(bias, isbf, c0 + n);
            if (ELU) v = (v > 0.0f) ? v : expm1f(v);
            vv[n] = v;
        }
        if (OBF) {
            unsigned* Hrow = (unsigned*)((unsigned short*)H + (size_t)node * FOUT + c0);
#pragma unroll
            for (int n = 0; n < TN; n += 2)
                Hrow[n / 2] = packbf2(vv[n], vv[n + 1]);
        } else {
            float* Hrow = (float*)H + (size_t)node * FOUT + c0;
#pragma unroll
            for (int n = 0; n < TN; n += 4)
                *(float4*)(Hrow + n) = make_float4(vv[n], vv[n + 1], vv[n + 2], vv[n + 3]);
        }
    }
}

// --- aggregation: out[n] = di*Σ_e w'_e*H[src_e] + di^2*H[n] (+b, ELU)
// epk 4B/edge: src(17b) | q15(w')<<17, w' precomputed in k_fill.
// Node-parallel, LPN = F/8 lanes per node, uint4 (16B = 8 bf16) per
// lane -- halves gather/addr-calc/decode instruction count vs uint2
// (r14); per-edge gather stays cache-line-contiguous (128B/64B).
// Unroll 4 + software pipeline; fp32 accumulation, dual accumulators.
template <int F, bool BIAS, bool ELU>
__global__ __launch_bounds__(256) void k_agg(const uint4* __restrict__ Hb,
                                             const int* __restrict__ offsets,
                                             const int* __restrict__ counts,
                                             const unsigned* __restrict__ epk,
                                             const float* __restrict__ dinv,
                                             const void* __restrict__ bias,
                                             const int* __restrict__ flags,
                                             uint4* __restrict__ outb) {
    constexpr int LPN = F / 8;        // lanes per node (uint4 per lane)
    constexpr int NPB = 256 / LPN;    // nodes per block
    constexpr float QS = 1.0f / Q15;
    int t = threadIdx.x;
    int lane = t % LPN;
    int g = t / LPN;
    int node = blockIdx.x * NPB + g;
    if (node >= N) return;
    float di = dinv[node];
    uint4 hu = Hb[(size_t)node * LPN + lane];
    float4 hA = bf4tof4(make_uint2(hu.x, hu.y));
    float4 hB = bf4tof4(make_uint2(hu.z, hu.w));
    float4 aA0 = make_float4(0.f, 0.f, 0.f, 0.f);
    float4 aA1 = make_float4(0.f, 0.f, 0.f, 0.f);
    float4 aB0 = make_float4(0.f, 0.f, 0.f, 0.f);
    float4 aB1 = make_float4(0.f, 0.f, 0.f, 0.f);
    int p = offsets[node];
    int pend = p + counts[node];

    unsigned eA[4];
    bool have = (p + 4 <= pend);
    if (have) {
#pragma unroll
        for (int j = 0; j < 4; j++) eA[j] = epk[p + j];
    }
    while (have) {
        // issue 4 independent 16B gathers
        uint4 gg[4];
#pragma unroll
        for (int j = 0; j < 4; j++)
            gg[j] = Hb[(size_t)(eA[j] & 0x1FFFFu) * LPN + lane];
        float w[4];
#pragma unroll
        for (int j = 0; j < 4; j++) w[j] = (float)(eA[j] >> 17) * QS;
        p += 4;
        bool nxt = (p + 4 <= pend);
        unsigned eB[4];
        if (nxt) {
#pragma unroll
            for (int j = 0; j < 4; j++) eB[j] = epk[p + j];
        }
        // accumulate current batch (drains gather vmcnt; next epk loads
        // already in flight)
#pragma unroll
        for (int j = 0; j < 4; j += 2) {
            float4 l0 = bf4tof4(make_uint2(gg[j].x, gg[j].y));
            float4 u0 = bf4tof4(make_uint2(gg[j].z, gg[j].w));
            float4 l1 = bf4tof4(make_uint2(gg[j + 1].x, gg[j + 1].y));
            float4 u1 = bf4tof4(make_uint2(gg[j + 1].z, gg[j + 1].w));
            aA0.x += l0.x * w[j]; aA0.y += l0.y * w[j];
            aA0.z += l0.z * w[j]; aA0.w += l0.w * w[j];
            aB0.x += u0.x * w[j]; aB0.y += u0.y * w[j];
            aB0.z += u0.z * w[j]; aB0.w += u0.w * w[j];
            aA1.x += l1.x * w[j + 1]; aA1.y += l1.y * w[j + 1];
            aA1.z += l1.z * w[j + 1]; aA1.w += l1.w * w[j + 1];
            aB1.x += u1.x * w[j + 1]; aB1.y += u1.y * w[j + 1];
            aB1.z += u1.z * w[j + 1]; aB1.w += u1.w * w[j + 1];
        }
#pragma unroll
        for (int j = 0; j < 4; j++) eA[j] = eB[j];
        have = nxt;
    }
    // tail: scalar
    for (; p < pend; p++) {
        unsigned e = epk[p];
        uint4 gv = Hb[(size_t)(e & 0x1FFFFu) * LPN + lane];
        float w = (float)(e >> 17) * QS;
        float4 lo = bf4tof4(make_uint2(gv.x, gv.y));
        float4 hi = bf4tof4(make_uint2(gv.z, gv.w));
        aA0.x += lo.x * w; aA0.y += lo.y * w;
        aA0.z += lo.z * w; aA0.w += lo.w * w;
        aB0.x += hi.x * w; aB0.y += hi.y * w;
        aB0.z += hi.z * w; aB0.w += hi.w * w;
    }
    float4 accA, accB;
    accA.x = aA0.x + aA1.x; accA.y = aA0.y + aA1.y;
    accA.z = aA0.z + aA1.z; accA.w = aA0.w + aA1.w;
    accB.x = aB0.x + aB1.x; accB.y = aB0.y + aB1.y;
    accB.z = aB0.z + aB1.z; accB.w = aB0.w + aB1.w;
    float sw = di * di;
    accA.x = accA.x * di + hA.x * sw;
    accA.y = accA.y * di + hA.y * sw;
    accA.z = accA.z * di + hA.z * sw;
    accA.w = accA.w * di + hA.w * sw;
    accB.x = accB.x * di + hB.x * sw;
    accB.y = accB.y * di + hB.y * sw;
    accB.z = accB.z * di + hB.z * sw;
    accB.w = accB.w * di + hB.w * sw;
    if (BIAS) {
        int fb = lane * 8;
        int isbf = flags[1];
        accA.x += ldf(bias, isbf, fb);
        accA.y += ldf(bias, isbf, fb + 1);
        accA.z += ldf(bias, isbf, fb + 2);
        accA.w += ldf(bias, isbf, fb + 3);
        accB.x += ldf(bias, isbf, fb + 4);
        accB.y += ldf(bias, isbf, fb + 5);
        accB.z += ldf(bias, isbf, fb + 6);
        accB.w += ldf(bias, isbf, fb + 7);
    }
    if (ELU) {
        accA.x = (accA.x > 0.0f) ? accA.x : expm1f(accA.x);
        accA.y = (accA.y > 0.0f) ? accA.y : expm1f(accA.y);
        accA.z = (accA.z > 0.0f) ? accA.z : expm1f(accA.z);
        accA.w = (accA.w > 0.0f) ? accA.w : expm1f(accA.w);
        accB.x = (accB.x > 0.0f) ? accB.x : expm1f(accB.x);
        accB.y = (accB.y > 0.0f) ? accB.y : expm1f(accB.y);
        accB.z = (accB.z > 0.0f) ? accB.z : expm1f(accB.z);
        accB.w = (accB.w > 0.0f) ? accB.w : expm1f(accB.w);
    }
    uint2 oA = f4tobf4(accA);
    uint2 oB = f4tobf4(accB);
    outb[(size_t)node * LPN + lane] = make_uint4(oA.x, oA.y, oB.x, oB.y);
}

// diagnostic fallback: if ws_size too small, emit sentinel 123.0
__global__ void k_sentinel(float* out, int n) {
    int i = blockIdx.x * blockDim.x + threadIdx.x;
    if (i < n) out[i] = 123.0f;
}

extern "C" void kernel_launch(void* const* d_in, const int* in_sizes, int n_in,
                              void* d_out, int out_size, void* d_ws, size_t ws_size,
                              hipStream_t stream) {
    const void* x  = d_in[0];
    const void* ei = d_in[1];
    const void* ea = d_in[2];
    const void* W1 = d_in[3];
    const void* b1 = d_in[4];
    const void* W2 = d_in[5];
    const void* b2 = d_in[6];
    const void* W3 = d_in[7];
    const void* b3 = d_in[8];
    float* out = (float*)d_out;

    // workspace layout (256B aligned)
    char* ws = (char*)d_ws;
    size_t off = 0;
    auto alloc = [&](size_t bytes) {
        off = (off + 255) & ~(size_t)255;
        size_t r = off;
        off += bytes;
        return r;
    };
    float* dinv    = (float*)(ws + alloc((size_t)N * 4));
    int*   counts  = (int*)  (ws + alloc((size_t)N * 4));
    int*   offsets = (int*)  (ws + alloc((size_t)N * 4));
    int*   bkt_cnt = (int*)  (ws + alloc((size_t)NBKT * 4));
    int*   bkt_off = (int*)  (ws + alloc((size_t)(NBKT + 1) * 4));
    int*   bkt_cur = (int*)  (ws + alloc((size_t)NBKT * 4));
    int*   flags   = (int*)  (ws + alloc(256));
    unsigned* epk  = (unsigned*)(ws + alloc((size_t)E * 4));
    // bf16 feature buffers: N*64*2 = 12.8MB each; allocated back-to-back
    // (12.8MB is 256B-aligned) so tmp (E*8 = 25.6MB) aliases bufA+bufB.
    // tmp's last read (k_fill) precedes bufA's first write (L1 GEMM).
    unsigned short* bufA = (unsigned short*)(ws + alloc((size_t)N * 64 * 2));
    unsigned short* bufB = (unsigned short*)(ws + alloc((size_t)N * 64 * 2));
    size_t need = off;
    int2* tmp = (int2*)bufA;

    if (ws_size < need) {
        hipLaunchKernelGGL(k_sentinel, dim3((N * 128 + 255) / 256), dim3(256), 0, stream,
                           out, N * 128);
        return;
    }

    const int gH = (E + HIST_EPB - 1) / HIST_EPB;   // 782
    const int gS = (E + SC_EPB - 1) / SC_EPB;       // 782

    hipLaunchKernelGGL(k_probe, dim3(1), dim3(256), 0, stream, ei, x, flags, bkt_cnt);
    hipLaunchKernelGGL(k_hist, dim3(gH), dim3(512), 0, stream, ei, flags, bkt_cnt);
    hipLaunchKernelGGL(k_bscan, dim3(1), dim3(256), 0, stream, bkt_cnt, bkt_off, bkt_cur);
    hipLaunchKernelGGL(k_scatter, dim3(gS), dim3(512), 0, stream, ei, flags, ea, bkt_cur, tmp);
    hipLaunchKernelGGL(k_nodecnt, dim3(NBKT), dim3(256), 0, stream, tmp, bkt_off,
                       counts, offsets, dinv);
    hipLaunchKernelGGL(k_fill, dim3(NBKT), dim3(256), 0, stream, tmp, bkt_off,
                       offsets, dinv, epk);

    // L1: t1 = x@W1 (bufA, F=32 bf16); a1 = ELU(agg(t1)+b1) (bufB bf16)
    hipLaunchKernelGGL((k_gemm<128, 32, 2, 4, 32, 1, true, false, false>),
                       dim3((N + 63) / 64), dim3(256), 0, stream, x, W1, nullptr, flags, bufA);
    hipLaunchKernelGGL((k_agg<32, true, true>), dim3((N + 63) / 64), dim3(256), 0, stream,
                       (const uint4*)bufA, offsets, counts, epk, dinv, b1, flags, (uint4*)bufB);
    // L2: s2 = agg(a1) (bufA bf16); h2 = ELU(s2@W2+b2) (bufB, F=64 bf16)
    hipLaunchKernelGGL((k_agg<32, false, false>), dim3((N + 63) / 64), dim3(256), 0, stream,
                       (const uint4*)bufB, offsets, counts, epk, dinv, nullptr, flags, (uint4*)bufA);
    hipLaunchKernelGGL((k_gemm<32, 64, 4, 4, 32, 2, true, true, true>),
                       dim3((N + 63) / 64), dim3(256), 0, stream, bufA, W2, b2, flags, bufB);
    // L3: s3 = agg(h2) (bufA, F=64 bf16); out = s3@W3+b3 (d_out fp32)
    hipLaunchKernelGGL((k_agg<64, false, false>), dim3((N + 31) / 32), dim3(256), 0, stream,
                       (const uint4*)bufB, offsets, counts, epk, dinv, nullptr, flags, (uint4*)bufA);
    hipLaunchKernelGGL((k_gemm<64, 128, 4, 8, 32, 2, false, true, false>),
                       dim3((N + 63) / 64), dim3(256), 0, stream, bufA, W3, b3, flags, out);
}